// Round 10
// baseline (67.602 us; speedup 1.0000x reference)
//
#include <hip/hip_runtime.h>

#define NBINS 15
#define NBLK  2048   // 8 blocks/CU on 256 CUs; 8 float4-tiles per thread

typedef float f4 __attribute__((ext_vector_type(4)));
typedef int   i4 __attribute__((ext_vector_type(4)));

// ---- inline-asm load / counted-wait primitives (compiler cannot sink these) ----
#define GLD_F4(dst, p) asm volatile("global_load_dwordx4 %0, %1, off" : "=v"(dst) : "v"(p))
#define GLD_I4(dst, p) asm volatile("global_load_dwordx4 %0, %1, off" : "=v"(dst) : "v"(p))
// Counted wait: N loads may stay in flight. sched_barrier(0) right after keeps
// the dependent VALU from being hoisted above the wait (guide rule #18).
#define WAITV(n)                                                                \
    do {                                                                        \
        asm volatile("s_waitcnt vmcnt(" #n ")" ::: "memory");                   \
        __builtin_amdgcn_sched_barrier(0);                                      \
    } while (0)

// Per-element update on NAMED scalar accumulators (VGPR-resident).
// bin k covers (k/15,(k+1)/15] -> ceilf(cv*15) == k+1 (float compare, no cvt).
// cv<=0 -> ceil<=0 matches nothing; uniform(0,1) -> ceil<=15. d = cv-(pred==lab).
#define ECE_ELEM(cv_, pr_, lb_)                                                 \
    do {                                                                        \
        float cv = (cv_);                                                       \
        float bf = ceilf(cv * 15.0f);                                           \
        float d = cv - (((pr_) == (lb_)) ? 1.0f : 0.0f);                        \
        a0  += (bf == 1.0f)  ? d : 0.0f;  a1  += (bf == 2.0f)  ? d : 0.0f;      \
        a2  += (bf == 3.0f)  ? d : 0.0f;  a3  += (bf == 4.0f)  ? d : 0.0f;      \
        a4  += (bf == 5.0f)  ? d : 0.0f;  a5  += (bf == 6.0f)  ? d : 0.0f;      \
        a6  += (bf == 7.0f)  ? d : 0.0f;  a7  += (bf == 8.0f)  ? d : 0.0f;      \
        a8  += (bf == 9.0f)  ? d : 0.0f;  a9  += (bf == 10.0f) ? d : 0.0f;      \
        a10 += (bf == 11.0f) ? d : 0.0f;  a11 += (bf == 12.0f) ? d : 0.0f;      \
        a12 += (bf == 13.0f) ? d : 0.0f;  a13 += (bf == 14.0f) ? d : 0.0f;      \
        a14 += (bf == 15.0f) ? d : 0.0f;                                        \
    } while (0)

#define ECE_TILE(c, p, l)                                                       \
    do {                                                                        \
        ECE_ELEM((c).x, (p).x, (l).x); ECE_ELEM((c).y, (p).y, (l).y);           \
        ECE_ELEM((c).z, (p).z, (l).z); ECE_ELEM((c).w, (p).w, (l).w);           \
    } while (0)

// Issue one phase's 6 loads (2 tiles x {conf,pred,lab}) and advance cursors.
#define PHASE_LOAD(C0, P0, L0, C1, P1, L1)                                      \
    do {                                                                        \
        GLD_F4(C0, cl);          GLD_F4(C1, cl + stride);                       \
        GLD_I4(P0, pl);          GLD_I4(P1, pl + stride);                       \
        GLD_I4(L0, ll);          GLD_I4(L1, ll + stride);                       \
        cl += 2 * stride; pl += 2 * stride; ll += 2 * stride;                   \
    } while (0)

#define WAVE_RED(A)                                                             \
    do {                                                                        \
        A += __shfl_xor(A, 1, 64);  A += __shfl_xor(A, 2, 64);                  \
        A += __shfl_xor(A, 4, 64);  A += __shfl_xor(A, 8, 64);                  \
        A += __shfl_xor(A, 16, 64); A += __shfl_xor(A, 32, 64);                 \
    } while (0)

__global__ __launch_bounds__(256) void ece_main(const float* __restrict__ conf,
                                                const int* __restrict__ pred,
                                                const int* __restrict__ lab,
                                                float* __restrict__ ws,
                                                int nvec) {
    float a0 = 0.0f, a1 = 0.0f, a2 = 0.0f, a3 = 0.0f, a4 = 0.0f;
    float a5 = 0.0f, a6 = 0.0f, a7 = 0.0f, a8 = 0.0f, a9 = 0.0f;
    float a10 = 0.0f, a11 = 0.0f, a12 = 0.0f, a13 = 0.0f, a14 = 0.0f;

    const int tid    = blockIdx.x * blockDim.x + threadIdx.x;
    const int stride = gridDim.x * blockDim.x;

    bool pipe  = (nvec % stride) == 0;
    int  niter = pipe ? (nvec / stride) : 0;     // tiles per thread (8 expected)
    if (niter < 4 || (niter & 3)) pipe = false;  // need multiple of 4 (2 tiles/phase)

    if (pipe) {
        const f4* cl = (const f4*)conf + tid;
        const i4* pl = (const i4*)pred + tid;
        const i4* ll = (const i4*)lab  + tid;

        f4 cX0, cX1, cY0, cY1;
        i4 pX0, pX1, pY0, pY1, lX0, lX1, lY0, lY1;

        // Prefill: phase 0's data -> set X. 6 loads in flight.
        PHASE_LOAD(cX0, pX0, lX0, cX1, pX1, lX1);

        const int nphase = niter >> 1;           // 4 phases of 2 tiles
        // Steady state: issue next phase's 6 loads, wait for the previous 6
        // (vmcnt(6): the just-issued batch stays in flight), compute.
        for (int ph = 0; ph + 2 < nphase; ph += 2) {
            PHASE_LOAD(cY0, pY0, lY0, cY1, pY1, lY1);
            WAITV(6);
            ECE_TILE(cX0, pX0, lX0); ECE_TILE(cX1, pX1, lX1);

            PHASE_LOAD(cX0, pX0, lX0, cX1, pX1, lX1);
            WAITV(6);
            ECE_TILE(cY0, pY0, lY0); ECE_TILE(cY1, pY1, lY1);
        }
        // Phase nphase-2: load last pair -> Y, compute X.
        PHASE_LOAD(cY0, pY0, lY0, cY1, pY1, lY1);
        WAITV(6);
        ECE_TILE(cX0, pX0, lX0); ECE_TILE(cX1, pX1, lX1);
        // Final phase: drain and compute Y.
        WAITV(0);
        ECE_TILE(cY0, pY0, lY0); ECE_TILE(cY1, pY1, lY1);
    } else {
        // Generic fallback (any shape).
        const f4* c4 = (const f4*)conf;
        const i4* p4 = (const i4*)pred;
        const i4* l4 = (const i4*)lab;
        for (int i = tid; i < nvec; i += stride) {
            f4 c = c4[i]; i4 p = p4[i]; i4 l = l4[i];
            ECE_TILE(c, p, l);
        }
    }

    // Wave-level butterfly reduction (64 lanes) per bin.
    WAVE_RED(a0);  WAVE_RED(a1);  WAVE_RED(a2);  WAVE_RED(a3);  WAVE_RED(a4);
    WAVE_RED(a5);  WAVE_RED(a6);  WAVE_RED(a7);  WAVE_RED(a8);  WAVE_RED(a9);
    WAVE_RED(a10); WAVE_RED(a11); WAVE_RED(a12); WAVE_RED(a13); WAVE_RED(a14);

    // Block partials via LDS; plain store to a per-block slot (no init kernel,
    // no global atomics, no device fence -> R2-R4's ~330us fence cost avoided).
    __shared__ float s_h[4][16];
    int wave = threadIdx.x >> 6;
    int lane = threadIdx.x & 63;
    if (lane == 0) {
        s_h[wave][0]  = a0;  s_h[wave][1]  = a1;  s_h[wave][2]  = a2;
        s_h[wave][3]  = a3;  s_h[wave][4]  = a4;  s_h[wave][5]  = a5;
        s_h[wave][6]  = a6;  s_h[wave][7]  = a7;  s_h[wave][8]  = a8;
        s_h[wave][9]  = a9;  s_h[wave][10] = a10; s_h[wave][11] = a11;
        s_h[wave][12] = a12; s_h[wave][13] = a13; s_h[wave][14] = a14;
    }
    __syncthreads();
    if (threadIdx.x < NBINS) {
        int k = threadIdx.x;
        // Transposed layout ws[k*NBLK + block] -> coalesced reads in ece_final.
        ws[k * NBLK + blockIdx.x] =
            s_h[0][k] + s_h[1][k] + s_h[2][k] + s_h[3][k];
    }
}

__global__ __launch_bounds__(256) void ece_final(const float* __restrict__ ws,
                                                 float* __restrict__ out,
                                                 float inv_n) {
    __shared__ float s_f[16];
    int t   = threadIdx.x;
    int bin = t >> 4;
    int idx = t & 15;
    float p = 0.0f;
    if (t < 240) {
        const float* row = ws + bin * NBLK;
        for (int j = idx; j < NBLK; j += 16) p += row[j];
    }
    p += __shfl_xor(p, 1, 64); p += __shfl_xor(p, 2, 64);
    p += __shfl_xor(p, 4, 64); p += __shfl_xor(p, 8, 64);
    if (t < 240 && idx == 0) s_f[bin] = p;
    __syncthreads();

    float v = 0.0f;
    if (t < NBINS) v = fabsf(s_f[t]) * inv_n;
    WAVE_RED(v);
    if (t == 0) out[0] = v;
}

extern "C" void kernel_launch(void* const* d_in, const int* in_sizes, int n_in,
                              void* d_out, int out_size, void* d_ws, size_t ws_size,
                              hipStream_t stream) {
    const float* conf = (const float*)d_in[0];
    const int*   pred = (const int*)d_in[1];
    const int*   lab  = (const int*)d_in[2];
    float* ws  = (float*)d_ws;
    float* out = (float*)d_out;
    int n    = in_sizes[0];
    int nvec = n / 4;        // N = 16777216, divisible by 4

    ece_main<<<NBLK, 256, 0, stream>>>(conf, pred, lab, ws, nvec);
    ece_final<<<1, 256, 0, stream>>>(ws, out, 1.0f / (float)n);
}

// Round 11
// 64.859 us; speedup vs baseline: 1.0423x; 1.0423x over previous
//
#include <hip/hip_runtime.h>

#define NBINS 15
#define NBLK  2048   // 8 blocks/CU on 256 CUs

typedef float f4 __attribute__((ext_vector_type(4)));
typedef int   i4 __attribute__((ext_vector_type(4)));

// Branchless slot: bin k covers (k/15,(k+1)/15] -> ceil(cv*15) = k+1.
// slot = (min(unsigned(b1+15),31) & 15): b1 in [1,15] -> slot b1-1;
// b1==0 (cv<=0) -> 15 (trash); b1>16 or b1<0 -> 15 (trash). Slot 15 never read.
// Contribution d = cv - (pred==lab). hist is lane-private -> plain RMW, no atomic.
#define ECE_ELEM(cv_, pr_, lb_)                                                 \
    do {                                                                        \
        float cv = (cv_);                                                       \
        int b1 = (int)ceilf(cv * 15.0f);                                        \
        unsigned slot = min((unsigned)(b1 + 15), 31u) & 15u;                    \
        float d = cv - (((pr_) == (lb_)) ? 1.0f : 0.0f);                        \
        hw[slot << 6] += d;   /* ds_read_b32 + v_add_f32 + ds_write_b32 */      \
    } while (0)

#define ECE_TILE(c, p, l)                                                       \
    do {                                                                        \
        ECE_ELEM((c).x, (p).x, (l).x); ECE_ELEM((c).y, (p).y, (l).y);           \
        ECE_ELEM((c).z, (p).z, (l).z); ECE_ELEM((c).w, (p).w, (l).w);           \
    } while (0)

#define WAVE_RED(A)                                                             \
    do {                                                                        \
        A += __shfl_xor(A, 1, 64);  A += __shfl_xor(A, 2, 64);                  \
        A += __shfl_xor(A, 4, 64);  A += __shfl_xor(A, 8, 64);                  \
        A += __shfl_xor(A, 16, 64); A += __shfl_xor(A, 32, 64);                 \
    } while (0)

__global__ __launch_bounds__(256) void ece_main(const float* __restrict__ conf,
                                                const int* __restrict__ pred,
                                                const int* __restrict__ lab,
                                                float* __restrict__ ws,
                                                int nvec) {
    // hist[wave][slot][lane]: lane-private column -> bank = lane&31 always
    // (2-way lane aliasing is free, m136). 16 KiB -> 8 blocks/CU still fit.
    __shared__ float hist[4 * 16 * 64];
    for (int j = threadIdx.x; j < 4 * 16 * 64; j += 256) hist[j] = 0.0f;
    __syncthreads();

    const int wave = threadIdx.x >> 6;
    const int lane = threadIdx.x & 63;
    float* hw = &hist[(wave << 10) | lane];   // &hist[wave][0][lane]

    const f4* __restrict__ c4 = (const f4*)conf;
    const i4* __restrict__ p4 = (const i4*)pred;
    const i4* __restrict__ l4 = (const i4*)lab;

    const int tid    = blockIdx.x * blockDim.x + threadIdx.x;
    const int stride = gridDim.x * blockDim.x;

    int i = tid;
    // Unroll-by-2: 6 independent 16B loads per iteration (compiler-scheduled;
    // R8/R10 showed hand-pipelining is redundant-to-harmful in the warm regime).
    for (; i + stride < nvec; i += 2 * stride) {
        f4 c0 = c4[i];
        f4 c1 = c4[i + stride];
        i4 p0 = p4[i];
        i4 p1 = p4[i + stride];
        i4 l0 = l4[i];
        i4 l1 = l4[i + stride];
        ECE_TILE(c0, p0, l0);
        ECE_TILE(c1, p1, l1);
    }
    for (; i < nvec; i += stride) {
        f4 c = c4[i]; i4 p = p4[i]; i4 l = l4[i];
        ECE_TILE(c, p, l);
    }

    // Per-wave reduce: DS ops are in-order per wave, so our own writes are
    // visible to our reads without a barrier (validated in R6).
    __shared__ float s_blk[4][16];
#pragma unroll
    for (int k = 0; k < NBINS; ++k) {
        float f = hist[(wave << 10) | (k << 6) | lane];
        WAVE_RED(f);
        if (lane == 0) s_blk[wave][k] = f;
    }
    __syncthreads();

    // Block partials: plain store to a per-block slot (no init kernel, no
    // global atomics, no device fence -> R2-R4's ~330us fence cost avoided).
    if (threadIdx.x < NBINS) {
        int k = threadIdx.x;
        // Transposed layout ws[k*NBLK + block] -> coalesced reads in ece_final.
        ws[k * NBLK + blockIdx.x] =
            s_blk[0][k] + s_blk[1][k] + s_blk[2][k] + s_blk[3][k];
    }
}

__global__ __launch_bounds__(256) void ece_final(const float* __restrict__ ws,
                                                 float* __restrict__ out,
                                                 float inv_n) {
    __shared__ float s_f[16];
    int t   = threadIdx.x;
    int bin = t >> 4;
    int idx = t & 15;
    float p = 0.0f;
    if (t < 240) {
        const float* row = ws + bin * NBLK;
        for (int j = idx; j < NBLK; j += 16) p += row[j];
    }
    p += __shfl_xor(p, 1, 64); p += __shfl_xor(p, 2, 64);
    p += __shfl_xor(p, 4, 64); p += __shfl_xor(p, 8, 64);
    if (t < 240 && idx == 0) s_f[bin] = p;
    __syncthreads();

    float v = 0.0f;
    if (t < NBINS) v = fabsf(s_f[t]) * inv_n;
    WAVE_RED(v);
    if (t == 0) out[0] = v;
}

extern "C" void kernel_launch(void* const* d_in, const int* in_sizes, int n_in,
                              void* d_out, int out_size, void* d_ws, size_t ws_size,
                              hipStream_t stream) {
    const float* conf = (const float*)d_in[0];
    const int*   pred = (const int*)d_in[1];
    const int*   lab  = (const int*)d_in[2];
    float* ws  = (float*)d_ws;
    float* out = (float*)d_out;
    int n    = in_sizes[0];
    int nvec = n / 4;        // N = 16777216, divisible by 4

    ece_main<<<NBLK, 256, 0, stream>>>(conf, pred, lab, ws, nvec);
    ece_final<<<1, 256, 0, stream>>>(ws, out, 1.0f / (float)n);
}

// Round 12
// 46.431 us; speedup vs baseline: 1.4560x; 1.3969x over previous
//
#include <hip/hip_runtime.h>

#define NBINS 15
#define NREP 8            // global accumulator replicas (one per XCD)
#define REP_STRIDE 16
#define WS_WORDS (NREP * REP_STRIDE)

typedef float f4 __attribute__((ext_vector_type(4)));
typedef int   i4 __attribute__((ext_vector_type(4)));

// ws layout: replica r at [r*16 .. r*16+14] = per-bin sum of (conf - correct)

__global__ void ece_init(float* __restrict__ ws) {
    int t = threadIdx.x;
    if (t < WS_WORDS) ws[t] = 0.0f;
}

// Per-element update on NAMED scalar accumulators (VGPR-resident).
// bin k covers (k/15,(k+1)/15] -> ceilf(cv*15) == k+1 (float compare, no cvt).
// cv<=0 -> ceil<=0 matches nothing; uniform(0,1) -> ceil<=15. d = cv-(pred==lab).
#define ECE_ELEM(cv_, pr_, lb_)                                                 \
    do {                                                                        \
        float cv = (cv_);                                                       \
        float bf = ceilf(cv * 15.0f);                                           \
        float d = cv - (((pr_) == (lb_)) ? 1.0f : 0.0f);                        \
        a0  += (bf == 1.0f)  ? d : 0.0f;  a1  += (bf == 2.0f)  ? d : 0.0f;      \
        a2  += (bf == 3.0f)  ? d : 0.0f;  a3  += (bf == 4.0f)  ? d : 0.0f;      \
        a4  += (bf == 5.0f)  ? d : 0.0f;  a5  += (bf == 6.0f)  ? d : 0.0f;      \
        a6  += (bf == 7.0f)  ? d : 0.0f;  a7  += (bf == 8.0f)  ? d : 0.0f;      \
        a8  += (bf == 9.0f)  ? d : 0.0f;  a9  += (bf == 10.0f) ? d : 0.0f;      \
        a10 += (bf == 11.0f) ? d : 0.0f;  a11 += (bf == 12.0f) ? d : 0.0f;      \
        a12 += (bf == 13.0f) ? d : 0.0f;  a13 += (bf == 14.0f) ? d : 0.0f;      \
        a14 += (bf == 15.0f) ? d : 0.0f;                                        \
    } while (0)

#define ECE_TILE(c, p, l)                                                       \
    do {                                                                        \
        ECE_ELEM((c).x, (p).x, (l).x); ECE_ELEM((c).y, (p).y, (l).y);           \
        ECE_ELEM((c).z, (p).z, (l).z); ECE_ELEM((c).w, (p).w, (l).w);           \
    } while (0)

#define WAVE_RED(A)                                                             \
    do {                                                                        \
        A += __shfl_xor(A, 1, 64);  A += __shfl_xor(A, 2, 64);                  \
        A += __shfl_xor(A, 4, 64);  A += __shfl_xor(A, 8, 64);                  \
        A += __shfl_xor(A, 16, 64); A += __shfl_xor(A, 32, 64);                 \
    } while (0)

__global__ __launch_bounds__(256) void ece_main(const float* __restrict__ conf,
                                                const int* __restrict__ pred,
                                                const int* __restrict__ lab,
                                                float* __restrict__ ws,
                                                int nvec) {
    float a0 = 0.0f, a1 = 0.0f, a2 = 0.0f, a3 = 0.0f, a4 = 0.0f;
    float a5 = 0.0f, a6 = 0.0f, a7 = 0.0f, a8 = 0.0f, a9 = 0.0f;
    float a10 = 0.0f, a11 = 0.0f, a12 = 0.0f, a13 = 0.0f, a14 = 0.0f;

    const f4* __restrict__ c4 = (const f4*)conf;
    const i4* __restrict__ p4 = (const i4*)pred;
    const i4* __restrict__ l4 = (const i4*)lab;

    const int tid    = blockIdx.x * blockDim.x + threadIdx.x;
    const int stride = gridDim.x * blockDim.x;

    int i = tid;
    // Unroll-by-4: 12 independent 16B loads (192B/lane) in flight per iteration.
    // Attacks the ~27us latency intercept via MLP; VGPR rises to ~75 (6 w/SIMD).
    for (; i + 3 * stride < nvec; i += 4 * stride) {
        f4 c0 = c4[i];
        f4 c1 = c4[i + stride];
        f4 c2 = c4[i + 2 * stride];
        f4 c3 = c4[i + 3 * stride];
        i4 p0 = p4[i];
        i4 p1 = p4[i + stride];
        i4 p2 = p4[i + 2 * stride];
        i4 p3 = p4[i + 3 * stride];
        i4 l0 = l4[i];
        i4 l1 = l4[i + stride];
        i4 l2 = l4[i + 2 * stride];
        i4 l3 = l4[i + 3 * stride];

        ECE_TILE(c0, p0, l0);
        ECE_TILE(c1, p1, l1);
        ECE_TILE(c2, p2, l2);
        ECE_TILE(c3, p3, l3);
    }
    for (; i < nvec; i += stride) {
        f4 c = c4[i]; i4 p = p4[i]; i4 l = l4[i];
        ECE_TILE(c, p, l);
    }

    // Wave-level butterfly reduction (64 lanes) per bin.
    WAVE_RED(a0);  WAVE_RED(a1);  WAVE_RED(a2);  WAVE_RED(a3);  WAVE_RED(a4);
    WAVE_RED(a5);  WAVE_RED(a6);  WAVE_RED(a7);  WAVE_RED(a8);  WAVE_RED(a9);
    WAVE_RED(a10); WAVE_RED(a11); WAVE_RED(a12); WAVE_RED(a13); WAVE_RED(a14);

    // Block-level reduction through LDS, one global atomic per bin per block
    // into 8 replicas (proven cheapest finalize path: final reads only 8x16).
    __shared__ float s_h[4][16];
    int wave = threadIdx.x >> 6;
    int lane = threadIdx.x & 63;
    if (lane == 0) {
        s_h[wave][0]  = a0;  s_h[wave][1]  = a1;  s_h[wave][2]  = a2;
        s_h[wave][3]  = a3;  s_h[wave][4]  = a4;  s_h[wave][5]  = a5;
        s_h[wave][6]  = a6;  s_h[wave][7]  = a7;  s_h[wave][8]  = a8;
        s_h[wave][9]  = a9;  s_h[wave][10] = a10; s_h[wave][11] = a11;
        s_h[wave][12] = a12; s_h[wave][13] = a13; s_h[wave][14] = a14;
    }
    __syncthreads();
    if (threadIdx.x < NBINS) {
        int k = threadIdx.x;
        float s = s_h[0][k] + s_h[1][k] + s_h[2][k] + s_h[3][k];
        atomicAdd(ws + (blockIdx.x & (NREP - 1)) * REP_STRIDE + k, s);
    }
    // No fused finalize / __threadfence: per-wave device fences cost ~330 us
    // on gfx950 (R2-R4). The launch boundary publishes ws to ece_final.
}

__global__ void ece_final(const float* __restrict__ ws, float* __restrict__ out,
                          float inv_n) {
    int k = threadIdx.x;
    float v = 0.0f;
    if (k < NBINS) {
        float s = 0.0f;
#pragma unroll
        for (int r = 0; r < NREP; ++r) s += ws[r * REP_STRIDE + k];
        v = fabsf(s) * inv_n;
    }
    WAVE_RED(v);
    if (k == 0) out[0] = v;
}

extern "C" void kernel_launch(void* const* d_in, const int* in_sizes, int n_in,
                              void* d_out, int out_size, void* d_ws, size_t ws_size,
                              hipStream_t stream) {
    const float* conf = (const float*)d_in[0];
    const int*   pred = (const int*)d_in[1];
    const int*   lab  = (const int*)d_in[2];
    float* ws  = (float*)d_ws;
    float* out = (float*)d_out;
    int n    = in_sizes[0];
    int nvec = n / 4;        // N = 16777216, divisible by 4

    ece_init<<<1, 128, 0, stream>>>(ws);
    ece_main<<<2048, 256, 0, stream>>>(conf, pred, lab, ws, nvec);
    ece_final<<<1, 64, 0, stream>>>(ws, out, 1.0f / (float)n);
}

// Round 13
// 45.010 us; speedup vs baseline: 1.5019x; 1.0316x over previous
//
#include <hip/hip_runtime.h>

#define NBINS 15
#define NREP 8            // global accumulator replicas (one per XCD)
#define REP_STRIDE 16
#define WS_WORDS (NREP * REP_STRIDE)

typedef float f4 __attribute__((ext_vector_type(4)));
typedef int   i4 __attribute__((ext_vector_type(4)));

// ws layout: replica r at [r*16 .. r*16+14] = per-bin sum of (conf - correct),
// scaled by 2^18, stored as float.

__global__ void ece_init(float* __restrict__ ws) {
    int t = threadIdx.x;
    if (t < WS_WORDS) ws[t] = 0.0f;
}

// One mad per bin: acc += bit * dq. bit in {0,1} (u24), dq in [-2^18, 2^18) (i24).
// Non-volatile asm: ordering is purely dataflow -> scheduler stays free.
#define MADBIN(acc, kk)                                                         \
    do {                                                                        \
        unsigned bit = (h2 >> (kk)) & 1u;  /* v_bfe_u32 */                      \
        asm("v_mad_i32_i24 %0, %1, %2, %0" : "+v"(acc) : "v"(bit), "v"(dq));    \
    } while (0)

// Per-element update, integer path (39 instr/elem vs 51 for cmp/cndmask/add).
// bin k covers (k/15,(k+1)/15] -> ceil(cv*15) = k+1; one-hot h2 = 1<<(k+1).
// cv<=0 -> h2=1, bits 1..15 all zero -> no bin (matches reference validity).
// dq = round-trunc(cv*2^18) - (pred==lab)*2^18; truncation bias ~2e-6 on ECE.
#define ECE_ELEM(cv_, pr_, lb_)                                                 \
    do {                                                                        \
        float cv = (cv_);                                                       \
        float bf = ceilf(cv * 15.0f);                                           \
        unsigned h2 = 1u << (int)bf;                                            \
        int cvq = (int)(cv * 262144.0f);                                        \
        int dq = cvq - (((pr_) == (lb_)) ? 262144 : 0);                         \
        MADBIN(a0, 1);   MADBIN(a1, 2);   MADBIN(a2, 3);   MADBIN(a3, 4);       \
        MADBIN(a4, 5);   MADBIN(a5, 6);   MADBIN(a6, 7);   MADBIN(a7, 8);       \
        MADBIN(a8, 9);   MADBIN(a9, 10);  MADBIN(a10, 11); MADBIN(a11, 12);     \
        MADBIN(a12, 13); MADBIN(a13, 14); MADBIN(a14, 15);                      \
    } while (0)

#define ECE_TILE(c, p, l)                                                       \
    do {                                                                        \
        ECE_ELEM((c).x, (p).x, (l).x); ECE_ELEM((c).y, (p).y, (l).y);           \
        ECE_ELEM((c).z, (p).z, (l).z); ECE_ELEM((c).w, (p).w, (l).w);           \
    } while (0)

#define WAVE_RED(A)                                                             \
    do {                                                                        \
        A += __shfl_xor(A, 1, 64);  A += __shfl_xor(A, 2, 64);                  \
        A += __shfl_xor(A, 4, 64);  A += __shfl_xor(A, 8, 64);                  \
        A += __shfl_xor(A, 16, 64); A += __shfl_xor(A, 32, 64);                 \
    } while (0)

__global__ __launch_bounds__(256) void ece_main(const float* __restrict__ conf,
                                                const int* __restrict__ pred,
                                                const int* __restrict__ lab,
                                                float* __restrict__ ws,
                                                int nvec) {
    // Integer accumulators. Worst-case per-block bin sum: 8192 * 262143
    // = 2,147,475,456 < 2^31-1 -> exact, no overflow by construction.
    int a0 = 0, a1 = 0, a2 = 0, a3 = 0, a4 = 0, a5 = 0, a6 = 0, a7 = 0;
    int a8 = 0, a9 = 0, a10 = 0, a11 = 0, a12 = 0, a13 = 0, a14 = 0;

    const f4* __restrict__ c4 = (const f4*)conf;
    const i4* __restrict__ p4 = (const i4*)pred;
    const i4* __restrict__ l4 = (const i4*)lab;

    const int tid    = blockIdx.x * blockDim.x + threadIdx.x;
    const int stride = gridDim.x * blockDim.x;

    int i = tid;
    // Unroll-by-2 (proven equal-best memory schedule: R5/R8/R12 all ~46us).
    for (; i + stride < nvec; i += 2 * stride) {
        f4 c0 = c4[i];
        f4 c1 = c4[i + stride];
        i4 p0 = p4[i];
        i4 p1 = p4[i + stride];
        i4 l0 = l4[i];
        i4 l1 = l4[i + stride];
        ECE_TILE(c0, p0, l0);
        ECE_TILE(c1, p1, l1);
    }
    for (; i < nvec; i += stride) {
        f4 c = c4[i]; i4 p = p4[i]; i4 l = l4[i];
        ECE_TILE(c, p, l);
    }

    // Wave-level butterfly reduction (64 lanes) per bin, integer-exact.
    WAVE_RED(a0);  WAVE_RED(a1);  WAVE_RED(a2);  WAVE_RED(a3);  WAVE_RED(a4);
    WAVE_RED(a5);  WAVE_RED(a6);  WAVE_RED(a7);  WAVE_RED(a8);  WAVE_RED(a9);
    WAVE_RED(a10); WAVE_RED(a11); WAVE_RED(a12); WAVE_RED(a13); WAVE_RED(a14);

    // Block-level reduction through LDS (int, exact), then convert to float and
    // one global atomic per bin per block into 8 replicas (cheapest finalize).
    __shared__ int s_h[4][16];
    int wave = threadIdx.x >> 6;
    int lane = threadIdx.x & 63;
    if (lane == 0) {
        s_h[wave][0]  = a0;  s_h[wave][1]  = a1;  s_h[wave][2]  = a2;
        s_h[wave][3]  = a3;  s_h[wave][4]  = a4;  s_h[wave][5]  = a5;
        s_h[wave][6]  = a6;  s_h[wave][7]  = a7;  s_h[wave][8]  = a8;
        s_h[wave][9]  = a9;  s_h[wave][10] = a10; s_h[wave][11] = a11;
        s_h[wave][12] = a12; s_h[wave][13] = a13; s_h[wave][14] = a14;
    }
    __syncthreads();
    if (threadIdx.x < NBINS) {
        int k = threadIdx.x;
        int s = s_h[0][k] + s_h[1][k] + s_h[2][k] + s_h[3][k];
        atomicAdd(ws + (blockIdx.x & (NREP - 1)) * REP_STRIDE + k, (float)s);
    }
    // No fused finalize / __threadfence (R2-R4: ~330us fence cost on gfx950).
}

__global__ void ece_final(const float* __restrict__ ws, float* __restrict__ out,
                          float inv_n) {
    int k = threadIdx.x;
    float v = 0.0f;
    if (k < NBINS) {
        float s = 0.0f;
#pragma unroll
        for (int r = 0; r < NREP; ++r) s += ws[r * REP_STRIDE + k];
        v = fabsf(s) * inv_n;
    }
    WAVE_RED(v);
    if (k == 0) out[0] = v;
}

extern "C" void kernel_launch(void* const* d_in, const int* in_sizes, int n_in,
                              void* d_out, int out_size, void* d_ws, size_t ws_size,
                              hipStream_t stream) {
    const float* conf = (const float*)d_in[0];
    const int*   pred = (const int*)d_in[1];
    const int*   lab  = (const int*)d_in[2];
    float* ws  = (float*)d_ws;
    float* out = (float*)d_out;
    int n    = in_sizes[0];
    int nvec = n / 4;        // N = 16777216, divisible by 4

    ece_init<<<1, 128, 0, stream>>>(ws);
    ece_main<<<2048, 256, 0, stream>>>(conf, pred, lab, ws, nvec);
    // Scale by 2^-18 (dq quantization) and 1/N.
    ece_final<<<1, 64, 0, stream>>>(ws, out, 1.0f / ((float)n * 262144.0f));
}

// Round 14
// 42.470 us; speedup vs baseline: 1.5918x; 1.0598x over previous
//
#include <hip/hip_runtime.h>

#define NBINS 15
#define NBLK  2048   // 8 blocks/CU on 256 CUs

typedef float f4 __attribute__((ext_vector_type(4)));
typedef int   i4 __attribute__((ext_vector_type(4)));

// ws layout: ws[k*NBLK + b] = block b's partial sum for bin k, scaled 2^18.
// Every slot is written unconditionally each call -> no init kernel, no
// atomics, no fence (launch boundary publishes to ece_final).

// One mad per bin: acc += bit * dq. bit in {0,1} (u24), dq in [-2^18, 2^18) (i24).
// Non-volatile asm: ordering is purely dataflow -> scheduler stays free.
#define MADBIN(acc, kk)                                                         \
    do {                                                                        \
        unsigned bit = (h2 >> (kk)) & 1u;  /* v_bfe_u32 */                      \
        asm("v_mad_i32_i24 %0, %1, %2, %0" : "+v"(acc) : "v"(bit), "v"(dq));    \
    } while (0)

// Per-element update, integer path (~39 instr/elem).
// bin k covers (k/15,(k+1)/15] -> ceil(cv*15) = k+1; one-hot h2 = 1<<(k+1).
// cv<=0 -> h2=1, bits 1..15 all zero -> no bin (matches reference validity).
// dq = trunc(cv*2^18) - (pred==lab)*2^18; quantization bias ~2e-6 on ECE.
#define ECE_ELEM(cv_, pr_, lb_)                                                 \
    do {                                                                        \
        float cv = (cv_);                                                       \
        float bf = ceilf(cv * 15.0f);                                           \
        unsigned h2 = 1u << (int)bf;                                            \
        int cvq = (int)(cv * 262144.0f);                                        \
        int dq = cvq - (((pr_) == (lb_)) ? 262144 : 0);                         \
        MADBIN(a0, 1);   MADBIN(a1, 2);   MADBIN(a2, 3);   MADBIN(a3, 4);       \
        MADBIN(a4, 5);   MADBIN(a5, 6);   MADBIN(a6, 7);   MADBIN(a7, 8);       \
        MADBIN(a8, 9);   MADBIN(a9, 10);  MADBIN(a10, 11); MADBIN(a11, 12);     \
        MADBIN(a12, 13); MADBIN(a13, 14); MADBIN(a14, 15);                      \
    } while (0)

#define ECE_TILE(c, p, l)                                                       \
    do {                                                                        \
        ECE_ELEM((c).x, (p).x, (l).x); ECE_ELEM((c).y, (p).y, (l).y);           \
        ECE_ELEM((c).z, (p).z, (l).z); ECE_ELEM((c).w, (p).w, (l).w);           \
    } while (0)

#define WAVE_RED(A)                                                             \
    do {                                                                        \
        A += __shfl_xor(A, 1, 64);  A += __shfl_xor(A, 2, 64);                  \
        A += __shfl_xor(A, 4, 64);  A += __shfl_xor(A, 8, 64);                  \
        A += __shfl_xor(A, 16, 64); A += __shfl_xor(A, 32, 64);                 \
    } while (0)

__global__ __launch_bounds__(256) void ece_main(const float* __restrict__ conf,
                                                const int* __restrict__ pred,
                                                const int* __restrict__ lab,
                                                float* __restrict__ ws,
                                                int nvec) {
    // Integer accumulators. Worst-case per-block bin sum: 8192 * 262143
    // = 2,147,475,456 < 2^31-1 -> exact, no overflow by construction.
    int a0 = 0, a1 = 0, a2 = 0, a3 = 0, a4 = 0, a5 = 0, a6 = 0, a7 = 0;
    int a8 = 0, a9 = 0, a10 = 0, a11 = 0, a12 = 0, a13 = 0, a14 = 0;

    const f4* __restrict__ c4 = (const f4*)conf;
    const i4* __restrict__ p4 = (const i4*)pred;
    const i4* __restrict__ l4 = (const i4*)lab;

    const int tid    = blockIdx.x * blockDim.x + threadIdx.x;
    const int stride = gridDim.x * blockDim.x;

    int i = tid;
    // Unroll-by-2 (proven equal-best memory schedule: R5/R8/R12 all ~46us).
    for (; i + stride < nvec; i += 2 * stride) {
        f4 c0 = c4[i];
        f4 c1 = c4[i + stride];
        i4 p0 = p4[i];
        i4 p1 = p4[i + stride];
        i4 l0 = l4[i];
        i4 l1 = l4[i + stride];
        ECE_TILE(c0, p0, l0);
        ECE_TILE(c1, p1, l1);
    }
    for (; i < nvec; i += stride) {
        f4 c = c4[i]; i4 p = p4[i]; i4 l = l4[i];
        ECE_TILE(c, p, l);
    }

    // Wave-level butterfly reduction (64 lanes) per bin, integer-exact.
    WAVE_RED(a0);  WAVE_RED(a1);  WAVE_RED(a2);  WAVE_RED(a3);  WAVE_RED(a4);
    WAVE_RED(a5);  WAVE_RED(a6);  WAVE_RED(a7);  WAVE_RED(a8);  WAVE_RED(a9);
    WAVE_RED(a10); WAVE_RED(a11); WAVE_RED(a12); WAVE_RED(a13); WAVE_RED(a14);

    // Block-level reduction through LDS (int, exact), then ONE plain store per
    // bin to this block's exclusive slot. No atomics, no init, no fence.
    __shared__ int s_h[4][16];
    int wave = threadIdx.x >> 6;
    int lane = threadIdx.x & 63;
    if (lane == 0) {
        s_h[wave][0]  = a0;  s_h[wave][1]  = a1;  s_h[wave][2]  = a2;
        s_h[wave][3]  = a3;  s_h[wave][4]  = a4;  s_h[wave][5]  = a5;
        s_h[wave][6]  = a6;  s_h[wave][7]  = a7;  s_h[wave][8]  = a8;
        s_h[wave][9]  = a9;  s_h[wave][10] = a10; s_h[wave][11] = a11;
        s_h[wave][12] = a12; s_h[wave][13] = a13; s_h[wave][14] = a14;
    }
    __syncthreads();
    if (threadIdx.x < NBINS) {
        int k = threadIdx.x;
        int s = s_h[0][k] + s_h[1][k] + s_h[2][k] + s_h[3][k];
        // Transposed layout ws[k*NBLK + block] -> coalesced reads in ece_final.
        ws[k * NBLK + blockIdx.x] = (float)s;
    }
}

__global__ __launch_bounds__(1024) void ece_final(const float* __restrict__ ws,
                                                  float* __restrict__ out,
                                                  float inv_n) {
    // 960 active threads: 15 bins x 64 lanes. Each lane reads 2048/64 = 32
    // values with 4 independent partials -> ~8 latency rounds (vs R7's 128
    // serial rounds that cost ~16us). Wave-aligned groups (g = t>>6).
    __shared__ float s_f[16];
    int t    = threadIdx.x;
    int g    = t >> 6;       // bin group, 0..15 (group 15 idle)
    int lane = t & 63;
    float p0 = 0.0f, p1 = 0.0f, p2 = 0.0f, p3 = 0.0f;
    if (g < NBINS) {
        const float* row = ws + g * NBLK;
#pragma unroll
        for (int r = 0; r < 8; ++r) {
            p0 += row[lane + 256 * r];
            p1 += row[lane + 256 * r + 64];
            p2 += row[lane + 256 * r + 128];
            p3 += row[lane + 256 * r + 192];
        }
    }
    float p = (p0 + p1) + (p2 + p3);
    WAVE_RED(p);
    if (g < NBINS && lane == 0) s_f[g] = p;
    __syncthreads();

    if (t < 64) {
        float v = (t < NBINS) ? fabsf(s_f[t]) * inv_n : 0.0f;
        WAVE_RED(v);
        if (t == 0) out[0] = v;
    }
}

extern "C" void kernel_launch(void* const* d_in, const int* in_sizes, int n_in,
                              void* d_out, int out_size, void* d_ws, size_t ws_size,
                              hipStream_t stream) {
    const float* conf = (const float*)d_in[0];
    const int*   pred = (const int*)d_in[1];
    const int*   lab  = (const int*)d_in[2];
    float* ws  = (float*)d_ws;
    float* out = (float*)d_out;
    int n    = in_sizes[0];
    int nvec = n / 4;        // N = 16777216, divisible by 4

    ece_main<<<NBLK, 256, 0, stream>>>(conf, pred, lab, ws, nvec);
    // Scale by 2^-18 (dq quantization) and 1/N.
    ece_final<<<1, 1024, 0, stream>>>(ws, out, 1.0f / ((float)n * 262144.0f));
}